// Round 1
// baseline (31798.535 us; speedup 1.0000x reference)
//
#include <hip/hip_runtime.h>
#include <math.h>

#define BB 512
#define HH 512
#define FF 72
#define NCC 10
#define EE 64
#define TTRAJ 120
#define TOUT 120
#define INWW 713
#define GG 2048
#define LROWS 64
#define LHC 16

__device__ __forceinline__ float sigmoidf_(float x){ return 1.0f/(1.0f+__expf(-x)); }

// x_buf[b*H+j] = prelu(traj[b,t,:] . encW[j,:] + encB[j])
__global__ void traj_emb_kernel(const float* __restrict__ traj,
                                const float* __restrict__ encW,
                                const float* __restrict__ encB,
                                const float* __restrict__ prelu_a,
                                float* __restrict__ xout, int t)
{
    int idx = blockIdx.x*256 + threadIdx.x;
    int b = idx >> 9;
    int j = idx & (HH-1);
    float a = prelu_a[0];
    const float* tr = traj + (b*TTRAJ + t)*3;
    const float* w = encW + j*3;
    float v = encB[j] + tr[0]*w[0] + tr[1]*w[1] + tr[2]*w[2];
    xout[idx] = v >= 0.0f ? v : a*v;
}

// cond_out[b*H+j] = emb_b[j] + sum_i cond[b,i]*emb_W[j][72+i],  cond[b, c*64+e]=label[b,c]*ce[b,e]
__global__ void cond_kernel(const float* __restrict__ label,
                            const float* __restrict__ cemb,
                            const float* __restrict__ embW,
                            const float* __restrict__ embB,
                            float* __restrict__ cond_out)
{
    __shared__ float sl[NCC];
    __shared__ float se[EE];
    __shared__ float sc[NCC*EE];
    int b = blockIdx.x;
    int tid = threadIdx.x;
    if (tid < NCC) sl[tid] = label[b*NCC + tid];
    else if (tid >= 32 && tid < 32+EE) se[tid-32] = cemb[b*EE + (tid-32)];
    __syncthreads();
    for (int i = tid; i < NCC*EE; i += 256) sc[i] = sl[i>>6]*se[i&63];
    __syncthreads();
    for (int j = tid; j < HH; j += 256){
        const float* w = embW + (size_t)j*INWW + FF;
        float acc = embB[j];
        #pragma unroll 8
        for (int i = 0; i < NCC*EE; ++i) acc += sc[i]*w[i];
        cond_out[b*HH + j] = acc;
    }
}

// x[b*H+j] = prelu(cond_emb[b,j] + ts*emb_W[j][712] + sum_f prev_out[b,f]*emb_W[j][f])
__global__ void dec_emb_kernel(const float* __restrict__ dout,
                               const float* __restrict__ cond_emb,
                               const float* __restrict__ embW,
                               const float* __restrict__ prelu_a,
                               float* __restrict__ xout, int t, float ts)
{
    __shared__ float sp[FF];
    int b = blockIdx.x >> 1;
    int j = ((blockIdx.x & 1) << 8) + threadIdx.x;
    if (t > 0 && threadIdx.x < FF)
        sp[threadIdx.x] = dout[((size_t)b*TOUT + (t-1))*FF + threadIdx.x];
    __syncthreads();
    const float* w = embW + (size_t)j*INWW;
    float acc = cond_emb[b*HH + j] + ts*w[INWW-1];
    if (t > 0){
        #pragma unroll 8
        for (int f = 0; f < FF; ++f) acc += sp[f]*w[f];
    }
    float a = prelu_a[0];
    xout[b*HH + j] = acc >= 0.0f ? acc : a*acc;
}

// d_out[b,t,f] = h1[b,:] . outW[f,:] + outB[f]
__global__ void out_kernel(const float* __restrict__ h1,
                           const float* __restrict__ outW,
                           const float* __restrict__ outB,
                           float* __restrict__ dout, int t)
{
    __shared__ float sh[HH];
    int b = blockIdx.x;
    int tid = threadIdx.x; // 128
    for (int k = tid; k < HH; k += 128) sh[k] = h1[b*HH + k];
    __syncthreads();
    if (tid < FF){
        const float* w = outW + tid*HH;
        float acc = outB[tid];
        #pragma unroll 4
        for (int k = 0; k < HH; ++k) acc += sh[k]*w[k];
        dout[((size_t)b*TOUT + t)*FF + tid] = acc;
    }
}

// One LSTM layer step: gates = x@Wih.T + h@Whh.T + bih + bhh; fused cell update.
// Tile: 64 rows x (4 gates x 16 hcols). Grid (8, 32). Block 256 (16x16), thread: 4 rows x 4 gates.
__global__ __launch_bounds__(256)
void lstm_step_kernel(const float* __restrict__ x,
                      const float* __restrict__ h_in,
                      float* __restrict__ c_st,
                      float* __restrict__ h_out,
                      const float* __restrict__ Wih,
                      const float* __restrict__ Whh,
                      const float* __restrict__ bih,
                      const float* __restrict__ bhh)
{
    __shared__ float As[16][68];   // [kk][row]
    __shared__ float Bs[64][20];   // [gate*16+jj][kk]

    const int tid = threadIdx.x;
    const int tx = tid & 15;        // hcol within tile
    const int ty = tid >> 4;        // row group (4 rows each)
    const int row0 = blockIdx.x * LROWS;
    const int j0 = blockIdx.y * LHC;

    const int srow = tid >> 2;      // 0..63: A row / B col slot
    const int kgrp = tid & 3;       // k sub-offset *4
    const int g_of = srow >> 4;     // gate for B staging
    const int jj   = srow & 15;

    const float* Arow_x = x    + (size_t)(row0 + srow)*HH;
    const float* Arow_h = h_in + (size_t)(row0 + srow)*HH;
    const float* Brow_ih = Wih + (size_t)(g_of*HH + j0 + jj)*HH;
    const float* Brow_hh = Whh + (size_t)(g_of*HH + j0 + jj)*HH;

    float acc[4][4];
    #pragma unroll
    for (int i=0;i<4;i++)
        #pragma unroll
        for (int g=0;g<4;g++) acc[i][g]=0.0f;

    float4 aReg = *(const float4*)(Arow_x + kgrp*4);
    float4 bReg = *(const float4*)(Brow_ih + kgrp*4);

    for (int kt = 0; kt < 64; ++kt){
        __syncthreads();
        As[kgrp*4+0][srow] = aReg.x;
        As[kgrp*4+1][srow] = aReg.y;
        As[kgrp*4+2][srow] = aReg.z;
        As[kgrp*4+3][srow] = aReg.w;
        *(float4*)&Bs[srow][kgrp*4] = bReg;
        __syncthreads();
        if (kt+1 < 64){
            int k = (kt+1)*16;
            if (k < 512){
                aReg = *(const float4*)(Arow_x + k + kgrp*4);
                bReg = *(const float4*)(Brow_ih + k + kgrp*4);
            } else {
                aReg = *(const float4*)(Arow_h + (k-512) + kgrp*4);
                bReg = *(const float4*)(Brow_hh + (k-512) + kgrp*4);
            }
        }
        #pragma unroll
        for (int kb = 0; kb < 16; kb += 4){
            float4 av[4], bv[4];
            av[0] = *(const float4*)&As[kb+0][ty*4];
            av[1] = *(const float4*)&As[kb+1][ty*4];
            av[2] = *(const float4*)&As[kb+2][ty*4];
            av[3] = *(const float4*)&As[kb+3][ty*4];
            bv[0] = *(const float4*)&Bs[ 0+tx][kb];
            bv[1] = *(const float4*)&Bs[16+tx][kb];
            bv[2] = *(const float4*)&Bs[32+tx][kb];
            bv[3] = *(const float4*)&Bs[48+tx][kb];
            #pragma unroll
            for (int g=0; g<4; ++g){
                float4 bg = bv[g];
                acc[0][g] += av[0].x*bg.x + av[1].x*bg.y + av[2].x*bg.z + av[3].x*bg.w;
                acc[1][g] += av[0].y*bg.x + av[1].y*bg.y + av[2].y*bg.z + av[3].y*bg.w;
                acc[2][g] += av[0].z*bg.x + av[1].z*bg.y + av[2].z*bg.z + av[3].z*bg.w;
                acc[3][g] += av[0].w*bg.x + av[1].w*bg.y + av[2].w*bg.z + av[3].w*bg.w;
            }
        }
    }

    const int j = j0 + tx;
    const float bi0 = bih[j]        + bhh[j];
    const float bi1 = bih[HH+j]     + bhh[HH+j];
    const float bi2 = bih[2*HH+j]   + bhh[2*HH+j];
    const float bi3 = bih[3*HH+j]   + bhh[3*HH+j];
    #pragma unroll
    for (int i=0;i<4;i++){
        int b = row0 + ty*4 + i;
        float ig = sigmoidf_(acc[i][0] + bi0);
        float fg = sigmoidf_(acc[i][1] + bi1);
        float gg = tanhf(acc[i][2] + bi2);
        float og = sigmoidf_(acc[i][3] + bi3);
        float cp = c_st[(size_t)b*HH + j];
        float cn = fg*cp + ig*gg;
        c_st[(size_t)b*HH + j] = cn;
        h_out[(size_t)b*HH + j] = og*tanhf(cn);
    }
}

extern "C" void kernel_launch(void* const* d_in, const int* in_sizes, int n_in,
                              void* d_out, int out_size, void* d_ws, size_t ws_size,
                              hipStream_t stream)
{
    (void)in_sizes; (void)n_in; (void)out_size; (void)ws_size;
    const float* label   = (const float*)d_in[1];
    const float* cemb    = (const float*)d_in[2];
    const float* traj    = (const float*)d_in[3];
    const float* encW    = (const float*)d_in[4];
    const float* encB    = (const float*)d_in[5];
    const float* prelu_a = (const float*)d_in[6];
    const float* embW    = (const float*)d_in[7];
    const float* embB    = (const float*)d_in[8];
    const float* outW    = (const float*)d_in[9];
    const float* outB    = (const float*)d_in[10];
    const float* encWih  = (const float*)d_in[11];
    const float* encWhh  = (const float*)d_in[12];
    const float* encbih  = (const float*)d_in[13];
    const float* encbhh  = (const float*)d_in[14];
    const float* decWih  = (const float*)d_in[15];
    const float* decWhh  = (const float*)d_in[16];
    const float* decbih  = (const float*)d_in[17];
    const float* decbhh  = (const float*)d_in[18];
    float* out = (float*)d_out;

    float* ws = (float*)d_ws;
    const size_t BH = (size_t)BB*HH;
    float* hbuf = ws;             // [layer][parity][B*H] : 4*BH
    float* cbuf = ws + 4*BH;      // [layer][B*H]         : 2*BH
    float* xbuf = ws + 6*BH;      // [B*H]
    float* cond = ws + 7*BH;      // [B*H]

    // zero h and c
    hipMemsetAsync(hbuf, 0, 6*BH*sizeof(float), stream);

    cond_kernel<<<BB, 256, 0, stream>>>(label, cemb, embW, embB, cond);

    dim3 lgrid(BB/LROWS, HH/LHC);
    int p = 0;
    // ---- encoder ----
    for (int t = 0; t < TTRAJ; ++t){
        traj_emb_kernel<<<BB*HH/256, 256, 0, stream>>>(traj, encW, encB, prelu_a, xbuf, t);
        lstm_step_kernel<<<lgrid, 256, 0, stream>>>(
            xbuf, hbuf + (0*2+p)*BH, cbuf + 0*BH, hbuf + (0*2+(1-p))*BH,
            encWih + 0*(size_t)GG*HH, encWhh + 0*(size_t)GG*HH, encbih + 0*GG, encbhh + 0*GG);
        lstm_step_kernel<<<lgrid, 256, 0, stream>>>(
            hbuf + (0*2+(1-p))*BH, hbuf + (1*2+p)*BH, cbuf + 1*BH, hbuf + (1*2+(1-p))*BH,
            encWih + 1*(size_t)GG*HH, encWhh + 1*(size_t)GG*HH, encbih + 1*GG, encbhh + 1*GG);
        p = 1-p;
    }
    // ---- decoder ----
    for (int t = 0; t < TOUT; ++t){
        float ts = (float)(t+1) / (float)TOUT;
        dec_emb_kernel<<<BB*HH/256, 256, 0, stream>>>(out, cond, embW, prelu_a, xbuf, t, ts);
        lstm_step_kernel<<<lgrid, 256, 0, stream>>>(
            xbuf, hbuf + (0*2+p)*BH, cbuf + 0*BH, hbuf + (0*2+(1-p))*BH,
            decWih + 0*(size_t)GG*HH, decWhh + 0*(size_t)GG*HH, decbih + 0*GG, decbhh + 0*GG);
        lstm_step_kernel<<<lgrid, 256, 0, stream>>>(
            hbuf + (0*2+(1-p))*BH, hbuf + (1*2+p)*BH, cbuf + 1*BH, hbuf + (1*2+(1-p))*BH,
            decWih + 1*(size_t)GG*HH, decWhh + 1*(size_t)GG*HH, decbih + 1*GG, decbhh + 1*GG);
        out_kernel<<<BB, 128, 0, stream>>>(hbuf + (1*2+(1-p))*BH, outW, outB, out, t);
        p = 1-p;
    }
}

// Round 2
// 15082.391 us; speedup vs baseline: 2.1083x; 2.1083x over previous
//
#include <hip/hip_runtime.h>
#include <math.h>

#define BB 512
#define HH 512
#define FF 72
#define NCC 10
#define EE 64
#define TTRAJ 120
#define TOUT 120
#define INWW 713
#define GG 2048

typedef _Float16 f16x8 __attribute__((ext_vector_type(8)));
typedef float f32x4 __attribute__((ext_vector_type(4)));

__device__ __forceinline__ float sigmoidf_(float x){ return 1.0f/(1.0f+__expf(-x)); }

// Build fp16 Wcat[j][0:512]=Wih[j][:], Wcat[j][512:1024]=Whh[j][:]
__global__ void conv_wcat_kernel(const float* __restrict__ ih,
                                 const float* __restrict__ hh,
                                 _Float16* __restrict__ dst)
{
    int idx = blockIdx.x*256 + threadIdx.x;   // quad index: 2048*256
    int j  = idx >> 8;
    int k4 = (idx & 255) * 4;
    const float* src = (k4 < 512) ? (ih + (size_t)j*512 + k4)
                                  : (hh + (size_t)j*512 + (k4-512));
    float4 v = *(const float4*)src;
    _Float16* d = dst + (size_t)j*1024 + k4;
    d[0] = (_Float16)v.x; d[1] = (_Float16)v.y;
    d[2] = (_Float16)v.z; d[3] = (_Float16)v.w;
}

// x_buf[b*H+j] = fp16(prelu(traj[b,t,:] . encW[j,:] + encB[j]))
__global__ void traj_emb_kernel(const float* __restrict__ traj,
                                const float* __restrict__ encW,
                                const float* __restrict__ encB,
                                const float* __restrict__ prelu_a,
                                _Float16* __restrict__ xout, int t)
{
    int idx = blockIdx.x*256 + threadIdx.x;
    int b = idx >> 9;
    int j = idx & (HH-1);
    float a = prelu_a[0];
    const float* tr = traj + (b*TTRAJ + t)*3;
    const float* w = encW + j*3;
    float v = encB[j] + tr[0]*w[0] + tr[1]*w[1] + tr[2]*w[2];
    xout[idx] = (_Float16)(v >= 0.0f ? v : a*v);
}

// cond_out[b*H+j] = emb_b[j] + sum_i cond[b,i]*emb_W[j][72+i]
__global__ void cond_kernel(const float* __restrict__ label,
                            const float* __restrict__ cemb,
                            const float* __restrict__ embW,
                            const float* __restrict__ embB,
                            float* __restrict__ cond_out)
{
    __shared__ float sl[NCC];
    __shared__ float se[EE];
    __shared__ float sc[NCC*EE];
    int b = blockIdx.x;
    int tid = threadIdx.x;
    if (tid < NCC) sl[tid] = label[b*NCC + tid];
    else if (tid >= 32 && tid < 32+EE) se[tid-32] = cemb[b*EE + (tid-32)];
    __syncthreads();
    for (int i = tid; i < NCC*EE; i += 256) sc[i] = sl[i>>6]*se[i&63];
    __syncthreads();
    for (int j = tid; j < HH; j += 256){
        const float* w = embW + (size_t)j*INWW + FF;
        float acc = embB[j];
        #pragma unroll 8
        for (int i = 0; i < NCC*EE; ++i) acc += sc[i]*w[i];
        cond_out[b*HH + j] = acc;
    }
}

// x[b*H+j] = fp16(prelu(cond_emb[b,j] + ts*emb_W[j][712] + sum_f prev_out[b,f]*emb_W[j][f]))
__global__ void dec_emb_kernel(const float* __restrict__ dout,
                               const float* __restrict__ cond_emb,
                               const float* __restrict__ embW,
                               const float* __restrict__ prelu_a,
                               _Float16* __restrict__ xout, int t, float ts)
{
    __shared__ float sp[FF];
    int b = blockIdx.x >> 1;
    int j = ((blockIdx.x & 1) << 8) + threadIdx.x;
    if (t > 0 && threadIdx.x < FF)
        sp[threadIdx.x] = dout[((size_t)b*TOUT + (t-1))*FF + threadIdx.x];
    __syncthreads();
    const float* w = embW + (size_t)j*INWW;
    float acc = cond_emb[b*HH + j] + ts*w[INWW-1];
    if (t > 0){
        #pragma unroll 8
        for (int f = 0; f < FF; ++f) acc += sp[f]*w[f];
    }
    float a = prelu_a[0];
    xout[b*HH + j] = (_Float16)(acc >= 0.0f ? acc : a*acc);
}

// d_out[b,t,f] = h1[b,:] . outW[f,:] + outB[f]   (h1 in fp16)
__global__ void out_kernel(const _Float16* __restrict__ h1,
                           const float* __restrict__ outW,
                           const float* __restrict__ outB,
                           float* __restrict__ dout, int t)
{
    __shared__ float sh[HH];
    int b = blockIdx.x;
    int tid = threadIdx.x; // 128
    for (int k = tid; k < HH; k += 128) sh[k] = (float)h1[b*HH + k];
    __syncthreads();
    if (tid < FF){
        const float* w = outW + tid*HH;
        float acc = outB[tid];
        #pragma unroll 4
        for (int k = 0; k < HH; ++k) acc += sh[k]*w[k];
        dout[((size_t)b*TOUT + t)*FF + tid] = acc;
    }
}

// MFMA LSTM step. C[512 batch x 2048 gates] = [x|h] @ Wcat^T, fused cell update.
// Grid (8 row-tiles, 32 j-tiles), 256 threads = 4 waves.
// Wave w: rows [bx*64 + w*16, +16), cols {g*512 + by*16 + n : g=0..3, n=0..15}.
__global__ __launch_bounds__(256)
void lstm_mfma_kernel(const _Float16* __restrict__ Ax,
                      const _Float16* __restrict__ Ah,
                      float* __restrict__ c_st,
                      _Float16* __restrict__ h_out,
                      const _Float16* __restrict__ Wcat,
                      const float* __restrict__ bih,
                      const float* __restrict__ bhh)
{
    const int lane = threadIdx.x & 63;
    const int w    = threadIdx.x >> 6;   // wave id: row group
    const int m    = lane & 15;
    const int q    = lane >> 4;          // 0..3
    const int row0 = blockIdx.x * 64;
    const int j0   = blockIdx.y * 16;
    const int arow = row0 + w*16 + m;

    const _Float16* ax = Ax + (size_t)arow*HH + q*8;
    const _Float16* ah = Ah + (size_t)arow*HH + q*8;
    const _Float16* b0 = Wcat + ((size_t)(0*HH + j0 + m))*1024 + q*8;
    const _Float16* b1 = Wcat + ((size_t)(1*HH + j0 + m))*1024 + q*8;
    const _Float16* b2 = Wcat + ((size_t)(2*HH + j0 + m))*1024 + q*8;
    const _Float16* b3 = Wcat + ((size_t)(3*HH + j0 + m))*1024 + q*8;

    f32x4 acc0 = {0.f,0.f,0.f,0.f};
    f32x4 acc1 = {0.f,0.f,0.f,0.f};
    f32x4 acc2 = {0.f,0.f,0.f,0.f};
    f32x4 acc3 = {0.f,0.f,0.f,0.f};

    // K = 0..511 : x part
    #pragma unroll 4
    for (int c = 0; c < 16; ++c){
        f16x8 a = *(const f16x8*)(ax + c*32);
        acc0 = __builtin_amdgcn_mfma_f32_16x16x32_f16(a, *(const f16x8*)(b0 + c*32), acc0, 0,0,0);
        acc1 = __builtin_amdgcn_mfma_f32_16x16x32_f16(a, *(const f16x8*)(b1 + c*32), acc1, 0,0,0);
        acc2 = __builtin_amdgcn_mfma_f32_16x16x32_f16(a, *(const f16x8*)(b2 + c*32), acc2, 0,0,0);
        acc3 = __builtin_amdgcn_mfma_f32_16x16x32_f16(a, *(const f16x8*)(b3 + c*32), acc3, 0,0,0);
    }
    // K = 512..1023 : h part
    #pragma unroll 4
    for (int c = 0; c < 16; ++c){
        f16x8 a = *(const f16x8*)(ah + c*32);
        acc0 = __builtin_amdgcn_mfma_f32_16x16x32_f16(a, *(const f16x8*)(b0 + 512 + c*32), acc0, 0,0,0);
        acc1 = __builtin_amdgcn_mfma_f32_16x16x32_f16(a, *(const f16x8*)(b1 + 512 + c*32), acc1, 0,0,0);
        acc2 = __builtin_amdgcn_mfma_f32_16x16x32_f16(a, *(const f16x8*)(b2 + 512 + c*32), acc2, 0,0,0);
        acc3 = __builtin_amdgcn_mfma_f32_16x16x32_f16(a, *(const f16x8*)(b3 + 512 + c*32), acc3, 0,0,0);
    }

    // epilogue: lane holds (b = row0 + w*16 + q*4 + r, j = j0 + m) for r=0..3
    const int j = j0 + m;
    const float bi = bih[j]        + bhh[j];
    const float bf = bih[HH+j]     + bhh[HH+j];
    const float bg = bih[2*HH+j]   + bhh[2*HH+j];
    const float bo = bih[3*HH+j]   + bhh[3*HH+j];
    #pragma unroll
    for (int r = 0; r < 4; ++r){
        int b = row0 + w*16 + q*4 + r;
        float ig = sigmoidf_(acc0[r] + bi);
        float fg = sigmoidf_(acc1[r] + bf);
        float gg = tanhf(acc2[r] + bg);
        float og = sigmoidf_(acc3[r] + bo);
        float cp = c_st[(size_t)b*HH + j];
        float cn = fg*cp + ig*gg;
        c_st[(size_t)b*HH + j] = cn;
        h_out[(size_t)b*HH + j] = (_Float16)(og*tanhf(cn));
    }
}

extern "C" void kernel_launch(void* const* d_in, const int* in_sizes, int n_in,
                              void* d_out, int out_size, void* d_ws, size_t ws_size,
                              hipStream_t stream)
{
    (void)in_sizes; (void)n_in; (void)out_size; (void)ws_size;
    const float* label   = (const float*)d_in[1];
    const float* cemb    = (const float*)d_in[2];
    const float* traj    = (const float*)d_in[3];
    const float* encW    = (const float*)d_in[4];
    const float* encB    = (const float*)d_in[5];
    const float* prelu_a = (const float*)d_in[6];
    const float* embW    = (const float*)d_in[7];
    const float* embB    = (const float*)d_in[8];
    const float* outW    = (const float*)d_in[9];
    const float* outB    = (const float*)d_in[10];
    const float* encWih  = (const float*)d_in[11];
    const float* encWhh  = (const float*)d_in[12];
    const float* encbih  = (const float*)d_in[13];
    const float* encbhh  = (const float*)d_in[14];
    const float* decWih  = (const float*)d_in[15];
    const float* decWhh  = (const float*)d_in[16];
    const float* decbih  = (const float*)d_in[17];
    const float* decbhh  = (const float*)d_in[18];
    float* out = (float*)d_out;

    char* ws = (char*)d_ws;
    const size_t BHh = (size_t)BB*HH*sizeof(_Float16);   // 512 KB
    const size_t BHf = (size_t)BB*HH*sizeof(float);      // 1 MB
    // layout:
    //   0        : h bufs fp16, 4 x 512KB  (layer l parity p at (l*2+p))
    //   2MB      : c bufs f32, 2 x 1MB
    //   4MB      : xbuf fp16, 512KB
    //   4.5MB    : cond f32, 1MB
    //   5.5MB    : wcat fp16, 4 x 4MB (enc0, enc1, dec0, dec1)
    _Float16* hbuf = (_Float16*)(ws);
    float*    cbuf = (float*)   (ws + 4*BHh);
    _Float16* xbuf = (_Float16*)(ws + 4*BHh + 2*BHf);
    float*    cond = (float*)   (ws + 5*BHh + 2*BHf);
    _Float16* wcat = (_Float16*)(ws + 5*BHh + 3*BHf);
    const size_t BH = (size_t)BB*HH;
    const size_t WSZ = (size_t)GG*1024;   // elements per wcat matrix

    // zero h (fp16) + c (f32): contiguous 4MB
    hipMemsetAsync(hbuf, 0, 4*BHh + 2*BHf, stream);

    // weight conversion: enc layer0/1, dec layer0/1
    conv_wcat_kernel<<<2048, 256, 0, stream>>>(encWih,              encWhh,              wcat + 0*WSZ);
    conv_wcat_kernel<<<2048, 256, 0, stream>>>(encWih + (size_t)GG*HH, encWhh + (size_t)GG*HH, wcat + 1*WSZ);
    conv_wcat_kernel<<<2048, 256, 0, stream>>>(decWih,              decWhh,              wcat + 2*WSZ);
    conv_wcat_kernel<<<2048, 256, 0, stream>>>(decWih + (size_t)GG*HH, decWhh + (size_t)GG*HH, wcat + 3*WSZ);

    cond_kernel<<<BB, 256, 0, stream>>>(label, cemb, embW, embB, cond);

    dim3 lgrid(BB/64, HH/16);
    int p = 0;
    // ---- encoder ----
    for (int t = 0; t < TTRAJ; ++t){
        traj_emb_kernel<<<BB*HH/256, 256, 0, stream>>>(traj, encW, encB, prelu_a, xbuf, t);
        lstm_mfma_kernel<<<lgrid, 256, 0, stream>>>(
            xbuf, hbuf + (0*2+p)*BH, cbuf + 0*BH, hbuf + (0*2+(1-p))*BH,
            wcat + 0*WSZ, encbih, encbhh);
        lstm_mfma_kernel<<<lgrid, 256, 0, stream>>>(
            hbuf + (0*2+(1-p))*BH, hbuf + (1*2+p)*BH, cbuf + 1*BH, hbuf + (1*2+(1-p))*BH,
            wcat + 1*WSZ, encbih + GG, encbhh + GG);
        p = 1-p;
    }
    // ---- decoder ----
    for (int t = 0; t < TOUT; ++t){
        float ts = (float)(t+1) / (float)TOUT;
        dec_emb_kernel<<<BB*2, 256, 0, stream>>>(out, cond, embW, prelu_a, xbuf, t, ts);
        lstm_mfma_kernel<<<lgrid, 256, 0, stream>>>(
            xbuf, hbuf + (0*2+p)*BH, cbuf + 0*BH, hbuf + (0*2+(1-p))*BH,
            wcat + 2*WSZ, decbih, decbhh);
        lstm_mfma_kernel<<<lgrid, 256, 0, stream>>>(
            hbuf + (0*2+(1-p))*BH, hbuf + (1*2+p)*BH, cbuf + 1*BH, hbuf + (1*2+(1-p))*BH,
            wcat + 3*WSZ, decbih + GG, decbhh + GG);
        out_kernel<<<BB, 128, 0, stream>>>(hbuf + (1*2+(1-p))*BH, outW, outB, out, t);
        p = 1-p;
    }
}